// Round 6
// baseline (286.789 us; speedup 1.0000x reference)
//
#include <hip/hip_runtime.h>
#include <hip/hip_bf16.h>

typedef __attribute__((ext_vector_type(8))) short bf16x8;
typedef __attribute__((ext_vector_type(4))) float f32x4;

#define NBLK 256   // blocks; 512 threads each; 1 block/CU (88 KB LDS)

__device__ __forceinline__ unsigned short f2bf(float f) {
    unsigned u = __float_as_uint(f);
    return (unsigned short)((u + 0x7fffu + ((u >> 16) & 1u)) >> 16);
}

__device__ __forceinline__ bf16x8 pack8(float4 x, float4 y) {
    bf16x8 r;
    r[0] = (short)f2bf(x.x); r[1] = (short)f2bf(x.y);
    r[2] = (short)f2bf(x.z); r[3] = (short)f2bf(x.w);
    r[4] = (short)f2bf(y.x); r[5] = (short)f2bf(y.y);
    r[6] = (short)f2bf(y.z); r[7] = (short)f2bf(y.w);
    return r;
}

__device__ __forceinline__ float ftanh(float x) {
    float e = __expf(2.f * x);
    return 1.f - 2.f / (e + 1.f);
}

// One fused kernel. Edges processed in order, 32 per wave-supertile (2 MFMA
// tiles of 16). All 11 matrices (10 W_t + lin_w) staged in LDS as bf16
// A-fragments; per tile compute z_m = M_m * d for all 11, per-lane select
// z_{type(edge)} for the tanh path (m=10 is lin, always kept).
// Fragment layout (verified rounds 1-5): A row = lane&15 (output row within
// 16-block), k = (lane>>4)*8 + j; B col = lane&15 (edge), same k mapping;
// D col = lane&15 (edge), row = (lane>>4)*4 + r  -> float4 store per nt.
__global__ __launch_bounds__(512, 2) void k_fused(
    const int* __restrict__ ij, const float* __restrict__ desc,
    const float* __restrict__ layer1, const float* __restrict__ lin_w,
    const float* __restrict__ lin_b, float* __restrict__ out, int E) {

    __shared__ __align__(16) short wsm[11 * 512 * 8];   // 88 KiB

    // ---- stage all weights into LDS (bf16 MFMA A-fragment layout) ----
    for (int idx = threadIdx.x; idx < 11 * 512; idx += 512) {
        const int m = idx >> 9;          // matrix 0..10 (10 = lin_w)
        const int fl = idx & 511;        // frag-lane
        const int fi = fl >> 6, l = fl & 63;
        const int nt = fi >> 1, kk = fi & 1;
        const float* src = (m < 10) ? (layer1 + m * 4096) : lin_w;
        const float* sp = src + (nt * 16 + (l & 15)) * 64 + kk * 32 + (l >> 4) * 8;
        float4 x = *(const float4*)sp;
        float4 y = *(const float4*)(sp + 4);
        *(bf16x8*)(&wsm[idx * 8]) = pack8(x, y);
    }

    const int lane = threadIdx.x & 63;
    const int col = lane & 15;
    const int g = lane >> 4;
    const int kb = g * 8;

    float4 bias[4];
    #pragma unroll
    for (int nt = 0; nt < 4; ++nt) bias[nt] = *(const float4*)(lin_b + nt * 16 + g * 4);

    __syncthreads();

    const int gw = blockIdx.x * 8 + (threadIdx.x >> 6);
    const int nst = (E + 31) >> 5;       // 32-edge supertiles
    for (int s = gw; s < nst; s += NBLK * 8) {
        const int jb = s * 32;
        const int eA = jb + col, eB = jb + 16 + col;
        const int eAc = min(eA, E - 1), eBc = min(eB, E - 1);
        const int tyA = ij[eAc], tyB = ij[eBc];

        bf16x8 bA[2], bB[2];
        {
            const float* dp = desc + (size_t)eAc * 64 + kb;
            float4 x0 = *(const float4*)dp,        y0 = *(const float4*)(dp + 4);
            float4 x1 = *(const float4*)(dp + 32), y1 = *(const float4*)(dp + 36);
            bA[0] = pack8(x0, y0); bA[1] = pack8(x1, y1);
            const float* dq = desc + (size_t)eBc * 64 + kb;
            float4 p0 = *(const float4*)dq,        q0 = *(const float4*)(dq + 4);
            float4 p1 = *(const float4*)(dq + 32), q1 = *(const float4*)(dq + 36);
            bB[0] = pack8(p0, q0); bB[1] = pack8(p1, q1);
        }

        f32x4 aWA[4], aWB[4], zA[4], zB[4];
        #pragma unroll
        for (int nt = 0; nt < 4; ++nt) {
            aWA[nt] = (f32x4){0.f, 0.f, 0.f, 0.f};
            aWB[nt] = (f32x4){0.f, 0.f, 0.f, 0.f};
        }

        for (int m = 0; m < 11; ++m) {
            #pragma unroll
            for (int nt = 0; nt < 4; ++nt) {
                const bf16x8 f0 = *(const bf16x8*)(&wsm[((m * 8 + nt * 2 + 0) * 64 + lane) * 8]);
                const bf16x8 f1 = *(const bf16x8*)(&wsm[((m * 8 + nt * 2 + 1) * 64 + lane) * 8]);
                f32x4 z = {0.f, 0.f, 0.f, 0.f};
                z = __builtin_amdgcn_mfma_f32_16x16x32_bf16(f0, bA[0], z, 0, 0, 0);
                z = __builtin_amdgcn_mfma_f32_16x16x32_bf16(f1, bA[1], z, 0, 0, 0);
                zA[nt] = z;
                f32x4 y = {0.f, 0.f, 0.f, 0.f};
                y = __builtin_amdgcn_mfma_f32_16x16x32_bf16(f0, bB[0], y, 0, 0, 0);
                y = __builtin_amdgcn_mfma_f32_16x16x32_bf16(f1, bB[1], y, 0, 0, 0);
                zB[nt] = y;
            }
            if (m < 10) {
                #pragma unroll
                for (int nt = 0; nt < 4; ++nt) {
                    aWA[nt] = (tyA == m) ? zA[nt] : aWA[nt];
                    aWB[nt] = (tyB == m) ? zB[nt] : aWB[nt];
                }
            }
        }

        // epilogue: zA/zB now hold the lin results (m = 10)
        if (eA < E) {
            float* op = out + (size_t)eA * 64 + g * 4;
            #pragma unroll
            for (int nt = 0; nt < 4; ++nt) {
                f32x4 r;
                r[0] = ftanh(aWA[nt][0]) + zA[nt][0] + bias[nt].x;
                r[1] = ftanh(aWA[nt][1]) + zA[nt][1] + bias[nt].y;
                r[2] = ftanh(aWA[nt][2]) + zA[nt][2] + bias[nt].z;
                r[3] = ftanh(aWA[nt][3]) + zA[nt][3] + bias[nt].w;
                __builtin_nontemporal_store(r, (f32x4*)(op + nt * 16));
            }
        }
        if (eB < E) {
            float* op = out + (size_t)eB * 64 + g * 4;
            #pragma unroll
            for (int nt = 0; nt < 4; ++nt) {
                f32x4 r;
                r[0] = ftanh(aWB[nt][0]) + zB[nt][0] + bias[nt].x;
                r[1] = ftanh(aWB[nt][1]) + zB[nt][1] + bias[nt].y;
                r[2] = ftanh(aWB[nt][2]) + zB[nt][2] + bias[nt].z;
                r[3] = ftanh(aWB[nt][3]) + zB[nt][3] + bias[nt].w;
                __builtin_nontemporal_store(r, (f32x4*)(op + nt * 16));
            }
        }
    }
}

extern "C" void kernel_launch(void* const* d_in, const int* in_sizes, int n_in,
                              void* d_out, int out_size, void* d_ws, size_t ws_size,
                              hipStream_t stream) {
    const int* ij = (const int*)d_in[0];
    const float* desc = (const float*)d_in[1];
    const float* layer1 = (const float*)d_in[2];
    const float* lin_w = (const float*)d_in[3];
    const float* lin_b = (const float*)d_in[4];
    float* out = (float*)d_out;
    const int E = in_sizes[0];

    k_fused<<<NBLK, 512, 0, stream>>>(ij, desc, layer1, lin_w, lin_b, out, E);
}